// Round 16
// baseline (266.687 us; speedup 1.0000x reference)
//
#include <hip/hip_runtime.h>
#include <hip/hip_bf16.h>
#include <math.h>

// MAGNN-style hetero-GAT forward, R16.
// - tgemm: sched_barrier(0) between the 16 staging loads and the cvt/ds_write
//   loop. Forces all loads to issue before any consumer -> 64 VGPRs of load
//   results stay live -> ONE latency round instead of a serialized chain
//   (R13-R15 all showed VGPR=44 = compiler interleaving load/cvt/write).
// - Everything else identical to R15 (265us, absmax 3.9e-3).

#define HIDDEN 128
#define HEADS 4
#define NTGT 8192
#define NEDGE 100000
#define NNODES 100000

typedef __attribute__((ext_vector_type(8))) short bf16x8;
typedef __attribute__((ext_vector_type(4))) float f32x4;

__device__ inline short b16(float f)
{
    union { __hip_bfloat16 h; short s; } u;
    u.h = __float2bfloat16(f);
    return u.s;
}

__device__ inline float bf2f(unsigned short u)
{
    union { unsigned int i; float f; } v;
    v.i = (unsigned int)u << 16;
    return v.f;
}

struct GArgs {   // per-blockIdx.z pointers
    const void* A[4];
    const unsigned short* B[4];   // packed frag-major
    const float* bias[4];
    void* C[4];
    const int* rowmap[4];
    const float* vs[4];
    float* sem[4];
};

// ------------- transform GEMM: reg-staged bf16 LDS, fp32 A -> bf16 C -------
__global__ __launch_bounds__(256, 2)
void tgemm(GArgs g, int M)
{
    __shared__ unsigned short lds[32 * 512];   // 32KB bf16
    const int z = blockIdx.z;
    const float* Af = (const float*)g.A[z];
    const unsigned short* Bp = g.B[z];
    const float* bias = g.bias[z];
    const int* rowmap = g.rowmap[z];
    unsigned short* Ch = (unsigned short*)g.C[z];

    const int tid = threadIdx.x;
    const int w = tid >> 6, l = tid & 63;
    const int lr = l & 15, s4 = l >> 4;
    const int m0 = blockIdx.x * 32;

    {
        float4 v[16];
        #pragma unroll
        for (int q = 0; q < 8; ++q) {
            int rg = min(m0 + w * 8 + q, M - 1);
            const float* rowp = Af + (size_t)rg * 512;
            v[2 * q]     = *(const float4*)(rowp + l * 4);
            v[2 * q + 1] = *(const float4*)(rowp + 256 + l * 4);
        }
        // Pin ordering: ALL 16 loads issue before any cvt/ds_write below.
        __builtin_amdgcn_sched_barrier(0);
        #pragma unroll
        for (int q = 0; q < 8; ++q) {
            int rl = w * 8 + q;
            int rx = rl & 7;
            #pragma unroll
            for (int hh = 0; hh < 2; ++hh) {
                float4 vv = v[2 * q + hh];
                uint2 pk;
                pk.x = (unsigned int)(unsigned short)b16(vv.x) |
                       ((unsigned int)(unsigned short)b16(vv.y) << 16);
                pk.y = (unsigned int)(unsigned short)b16(vv.z) |
                       ((unsigned int)(unsigned short)b16(vv.w) << 16);
                int G = hh * 32 + (l >> 1);
                int slot = (G & ~7) | ((G & 7) ^ rx);
                *(uint2*)((char*)lds + (size_t)rl * 1024 + slot * 16 + (l & 1) * 8) = pk;
            }
        }
    }

    const int i = w & 1;
    const int jb = (w >> 1) * 4;

    f32x4 acc[4];
    #pragma unroll
    for (int jj = 0; jj < 4; ++jj) acc[jj] = (f32x4){0.f, 0.f, 0.f, 0.f};

    bf16x8 bbA[4], bbB[4];
    auto LDB = [&](int c, bf16x8 (&bb)[4]) {
        #pragma unroll
        for (int jj = 0; jj < 4; ++jj)
            bb[jj] = *(const bf16x8*)(Bp + ((size_t)(c * 8 + jb + jj) * 64 + l) * 8);
    };

    LDB(0, bbA);
    __syncthreads();

    const int r = i * 16 + lr;
    const int rx = r & 7;

    #pragma unroll
    for (int c = 0; c < 16; ++c) {
        int G = 4 * c + s4;
        int slot = (G & ~7) | ((G & 7) ^ rx);
        bf16x8 a = *(const bf16x8*)((const char*)lds + (size_t)r * 1024 + slot * 16);
        if (c & 1) {
            if (c + 1 < 16) LDB(c + 1, bbA);
            #pragma unroll
            for (int jj = 0; jj < 4; ++jj)
                acc[jj] = __builtin_amdgcn_mfma_f32_16x16x32_bf16(a, bbB[jj], acc[jj], 0, 0, 0);
        } else {
            if (c + 1 < 16) LDB(c + 1, bbB);
            #pragma unroll
            for (int jj = 0; jj < 4; ++jj)
                acc[jj] = __builtin_amdgcn_mfma_f32_16x16x32_bf16(a, bbA[jj], acc[jj], 0, 0, 0);
        }
    }

    #pragma unroll
    for (int rr = 0; rr < 4; ++rr) {
        int gm = m0 + i * 16 + s4 * 4 + rr;
        if (gm >= M) continue;
        size_t crow = (size_t)rowmap[gm];
        #pragma unroll
        for (int jj = 0; jj < 4; ++jj) {
            int n = (jb + jj) * 16 + lr;
            Ch[crow * 128 + n] = (unsigned short)b16(acc[jj][rr] + bias[n]);
        }
    }
}

// ---------------- unified MFMA GEMM (2-stage): C = A(->bf16) * Bpacked ------
template<int EPI, int NF, int MI, bool AB16, bool C16, int NFS>
__global__ __launch_bounds__(256)
void mgemm(GArgs g, int lda, int ldc,
           int aOffY, int bOffY, int cOffY, int nOffY, int M, int K)
{
    __shared__ float red[4];
    const int z = blockIdx.z;
    const unsigned short* Bp = g.B[z] + (size_t)blockIdx.y * bOffY;
    const float* bias = g.bias[z];
    const int* rowmap = g.rowmap[z];
    const int nbase = blockIdx.y * nOffY;
    float* Cf = nullptr;
    unsigned short* Ch = nullptr;
    if (g.C[z]) {
        if (C16) Ch = (unsigned short*)g.C[z] + (size_t)blockIdx.y * cOffY;
        else     Cf = (float*)g.C[z] + (size_t)blockIdx.y * cOffY;
    }
    const float* Af = nullptr;
    const unsigned short* Ah = nullptr;
    if (AB16) Ah = (const unsigned short*)g.A[z] + (size_t)blockIdx.y * aOffY;
    else      Af = (const float*)g.A[z] + (size_t)blockIdx.y * aOffY;

    const int tid = threadIdx.x;
    const int w = tid >> 6, l = tid & 63;
    const int lr = l & 15, lk = (l >> 4) * 8;
    const int m0 = blockIdx.x * (MI * 64) + w * (MI * 16);

    f32x4 acc[MI][NF];
    #pragma unroll
    for (int i = 0; i < MI; ++i)
        #pragma unroll
        for (int j = 0; j < NF; ++j)
            acc[i][j] = (f32x4){0.f, 0.f, 0.f, 0.f};

    float4 af0[MI][2], af1[MI][2];
    bf16x8 ah0[MI], ah1[MI];
    bf16x8 bb0[NF], bb1[NF];

    auto LD = [&](int k0, float4 (&af)[MI][2], bf16x8 (&ah)[MI], bf16x8 (&bb)[NF]) {
        #pragma unroll
        for (int i = 0; i < MI; ++i) {
            int row = min(m0 + i * 16 + lr, M - 1);
            if (AB16) {
                ah[i] = *(const bf16x8*)(Ah + (size_t)row * lda + k0 + lk);
            } else {
                const float* p = Af + (size_t)row * lda + k0 + lk;
                af[i][0] = *(const float4*)p;
                af[i][1] = *(const float4*)(p + 4);
            }
        }
        #pragma unroll
        for (int j = 0; j < NF; ++j)
            bb[j] = *(const bf16x8*)(Bp + ((size_t)((k0 >> 5) * NFS + j) * 64 + l) * 8);
    };

    auto CMP = [&](float4 (&af)[MI][2], bf16x8 (&ah)[MI], bf16x8 (&bb)[NF]) {
        bf16x8 a[MI];
        #pragma unroll
        for (int i = 0; i < MI; ++i) {
            if (AB16) {
                a[i] = ah[i];
            } else {
                bf16x8 r;
                r[0] = b16(af[i][0].x); r[1] = b16(af[i][0].y);
                r[2] = b16(af[i][0].z); r[3] = b16(af[i][0].w);
                r[4] = b16(af[i][1].x); r[5] = b16(af[i][1].y);
                r[6] = b16(af[i][1].z); r[7] = b16(af[i][1].w);
                a[i] = r;
            }
        }
        #pragma unroll
        for (int j = 0; j < NF; ++j)
            #pragma unroll
            for (int i = 0; i < MI; ++i)
                acc[i][j] = __builtin_amdgcn_mfma_f32_16x16x32_bf16(a[i], bb[j], acc[i][j], 0, 0, 0);
    };

    LD(0, af0, ah0, bb0);
    for (int k0 = 0; k0 < K; k0 += 64) {
        LD(k0 + 32, af1, ah1, bb1);
        CMP(af0, ah0, bb0);
        if (k0 + 64 < K) LD(k0 + 64, af0, ah0, bb0);
        CMP(af1, ah1, bb1);
    }

    if (EPI == 2) {
        const float* vs = g.vs[z];
        float local = 0.f;
        #pragma unroll
        for (int i = 0; i < MI; ++i) {
            int rbase = m0 + i * 16 + (l >> 4) * 4;
            #pragma unroll
            for (int r = 0; r < 4; ++r) {
                if (rbase + r >= M) continue;
                #pragma unroll
                for (int j = 0; j < NF; ++j) {
                    int n = nbase + j * 16 + lr;
                    local += tanhf(acc[i][j][r] + bias[n]) * vs[n];
                }
            }
        }
        #pragma unroll
        for (int o = 32; o; o >>= 1) local += __shfl_xor(local, o, 64);
        if (l == 0) red[w] = local;
        __syncthreads();
        if (tid == 0) atomicAdd(g.sem[z], red[0] + red[1] + red[2] + red[3]);
        return;
    }

    #pragma unroll
    for (int i = 0; i < MI; ++i) {
        int rbase = m0 + i * 16 + (l >> 4) * 4;
        #pragma unroll
        for (int r = 0; r < 4; ++r) {
            int gm = rbase + r;
            if (gm >= M) continue;
            size_t crow = rowmap ? (size_t)rowmap[gm] : (size_t)gm;
            #pragma unroll
            for (int j = 0; j < NF; ++j) {
                int n = nbase + j * 16 + lr;
                float v = acc[i][j][r];
                if (EPI == 0 && bias) v += bias[n];
                if (EPI == 1) v = v > 0.f ? v : expm1f(v);
                if (C16) Ch[crow * (size_t)ldc + n] = (unsigned short)b16(v);
                else     Cf[crow * (size_t)ldc + n] = v;
            }
        }
    }
}

// -------- fused combine+logits: h = b0*ob0+b1*ob1 (fp32 out, inline),
// logits = h @ Wo^T + bo. grid (128, 1, 2=nt); block = 64 rows, wave = 16.
__global__ __launch_bounds__(256)
void flogits(const unsigned short* __restrict__ obb,
             const unsigned short* __restrict__ wob,
             const float* __restrict__ betab,
             const float* __restrict__ bo0, const float* __restrict__ bo1,
             float* __restrict__ outbase, float* __restrict__ hout)
{
    const int nt = blockIdx.z;
    const unsigned short* o0 = obb + (size_t)(2 * nt) * NTGT * 512;
    const unsigned short* o1 = obb + (size_t)(2 * nt + 1) * NTGT * 512;
    const unsigned short* Bp = wob + (size_t)nt * 32768;
    const float* bo = nt ? bo1 : bo0;
    const float b0 = betab[nt * 2], b1 = betab[nt * 2 + 1];

    const int tid = threadIdx.x;
    const int w = tid >> 6, l = tid & 63;
    const int lr = l & 15, s4 = l >> 4, lk = s4 * 8;
    const int row = blockIdx.x * 64 + w * 16 + lr;
    float* hrow = hout + ((size_t)nt * NTGT + row) * 512;

    f32x4 acc[4];
    #pragma unroll
    for (int j = 0; j < 4; ++j) acc[j] = (f32x4){0.f, 0.f, 0.f, 0.f};

    for (int k0 = 0; k0 < 512; k0 += 32) {
        bf16x8 a0 = *(const bf16x8*)(o0 + (size_t)row * 512 + k0 + lk);
        bf16x8 a1 = *(const bf16x8*)(o1 + (size_t)row * 512 + k0 + lk);
        float hv[8];
        bf16x8 af;
        #pragma unroll
        for (int j = 0; j < 8; ++j) {
            hv[j] = b0 * bf2f((unsigned short)a0[j]) + b1 * bf2f((unsigned short)a1[j]);
            af[j] = b16(hv[j]);
        }
        *(float4*)(hrow + k0 + lk)     = make_float4(hv[0], hv[1], hv[2], hv[3]);
        *(float4*)(hrow + k0 + lk + 4) = make_float4(hv[4], hv[5], hv[6], hv[7]);
        #pragma unroll
        for (int j = 0; j < 4; ++j) {
            bf16x8 bb = *(const bf16x8*)(Bp + ((size_t)((k0 >> 5) * 4 + j) * 64 + l) * 8);
            acc[j] = __builtin_amdgcn_mfma_f32_16x16x32_bf16(af, bb, acc[j], 0, 0, 0);
        }
    }

    float* lout = outbase + (size_t)nt * NTGT * 64;
    #pragma unroll
    for (int r = 0; r < 4; ++r) {
        int gm = blockIdx.x * 64 + w * 16 + s4 * 4 + r;
        #pragma unroll
        for (int j = 0; j < 4; ++j) {
            int n = j * 16 + lr;
            lout[(size_t)gm * 64 + n] = acc[j][r] + bo[n];
        }
    }
}

// ------- pack fp32 weight matrices -> bf16 MFMA frag-major layout -----------
struct PackArgs {
    const float* src[22];
    unsigned short* dst[22];
    int n16[22], k32[22], ld[22];
};

__global__ __launch_bounds__(256)
void pack_kernel(PackArgs pa)
{
    int c = blockIdx.y;
    int idx = blockIdx.x * 256 + threadIdx.x;
    int tot = pa.n16[c] * pa.k32[c] * 64;
    if (idx >= tot) return;
    int l = idx & 63;
    int rest = idx >> 6;
    int j = rest % pa.n16[c];
    int k0 = rest / pa.n16[c];
    int row = j * 16 + (l & 15);
    int col = k0 * 32 + (l >> 4) * 8;
    const float* s = pa.src[c] + (size_t)row * pa.ld[c] + col;
    float4 u = *(const float4*)s;
    float4 v = *(const float4*)(s + 4);
    bf16x8 r;
    r[0] = b16(u.x); r[1] = b16(u.y); r[2] = b16(u.z); r[3] = b16(u.w);
    r[4] = b16(v.x); r[5] = b16(v.y); r[6] = b16(v.z); r[7] = b16(v.w);
    *(bf16x8*)(pa.dst[c] + (size_t)idx * 8) = r;
}

// --- watt (fused pack): wattp[idx] = b16( sum_d a[mp][h,d]*Wr[mp][h*128+d,k] )
struct WattArgs { const float* Wr[4]; const float* a[4]; };

__global__ __launch_bounds__(256)
void watt_kernel(WattArgs wa, unsigned short* __restrict__ wattp)
{
    int idx = blockIdx.x * 256 + threadIdx.x;   // 0..2047
    int f = idx >> 9;
    int r = idx & 511;
    int l = r >> 3;
    int e = r & 7;
    int row = l & 15;
    int k = f * 32 + ((l >> 4) << 3) + e;
    int mp = row >> 2, h = row & 3;
    const float* Wr = wa.Wr[mp];
    const float* a = wa.a[mp];
    float s = 0.f;
    #pragma unroll 4
    for (int d = 0; d < HIDDEN; ++d)
        s += a[h * HIDDEN + d] * Wr[(size_t)(h * HIDDEN + d) * HIDDEN + k];
    wattp[idx] = (unsigned short)b16(s);
}

// ---------------- CSR build: hist (with rank) / scan / scatter_esc ----------
struct EArgs { const int* eidx[4]; const int* etgt[4]; };

__global__ __launch_bounds__(256)
void hist_kernel(EArgs ea, int* __restrict__ cnt4, int* __restrict__ rank4, int E)
{
    int e = blockIdx.x * 256 + threadIdx.x;
    int mp = blockIdx.y;
    if (e < E)
        rank4[(size_t)mp * NEDGE + e] = atomicAdd(&cnt4[mp * NTGT + ea.etgt[mp][e]], 1);
}

__global__ __launch_bounds__(256)
void scan_kernel(int* __restrict__ cnt4, int* __restrict__ rowptr4)
{
    int mp = blockIdx.x;
    int* cnt = cnt4 + mp * NTGT;
    int* rowptr = rowptr4 + mp * (NTGT + 1);
    __shared__ int part[256];
    int t = threadIdx.x;
    int vals[32];
    int s = 0;
    int base = t * 32;
    #pragma unroll
    for (int i = 0; i < 32; ++i) { vals[i] = cnt[base + i]; s += vals[i]; }
    part[t] = s;
    __syncthreads();
    for (int o = 1; o < 256; o <<= 1) {
        int v = (t >= o) ? part[t - o] : 0;
        __syncthreads();
        part[t] += v;
        __syncthreads();
    }
    int off = (t == 0) ? 0 : part[t - 1];
    #pragma unroll
    for (int i = 0; i < 32; ++i) { rowptr[base + i] = off; off += vals[i]; }
    if (t == 255) rowptr[NTGT] = off;
}

// scatter (ATOMIC-FREE via rank) + edge exp-weight -> CSR-ordered 32B records
__global__ __launch_bounds__(256)
void scatter_esc(EArgs ea, const int* __restrict__ rowptr4,
                 const int* __restrict__ rank4, uint4* __restrict__ rec4,
                 const float* __restrict__ snode, int E)
{
    int e = blockIdx.x * 256 + threadIdx.x;
    int mp = blockIdx.y;
    if (e >= E) return;
    int t = ea.etgt[mp][e];
    int slot = rowptr4[mp * (NTGT + 1) + t] + rank4[(size_t)mp * NEDGE + e];

    const int* eidx = ea.eidx[mp];
    int i0 = eidx[e * 3 + 0], i1 = eidx[e * 3 + 1], i2 = eidx[e * 3 + 2];
    float4 s0 = *(const float4*)(snode + (size_t)i0 * 16 + mp * 4);
    float4 s1 = *(const float4*)(snode + (size_t)i1 * 16 + mp * 4);
    float4 s2 = *(const float4*)(snode + (size_t)i2 * 16 + mp * 4);
    const float inv3 = 1.f / 3.f;
    float es[4];
    es[0] = (s0.x + s1.x + s2.x) * inv3;
    es[1] = (s0.y + s1.y + s2.y) * inv3;
    es[2] = (s0.z + s1.z + s2.z) * inv3;
    es[3] = (s0.w + s1.w + s2.w) * inv3;
    #pragma unroll
    for (int h = 0; h < 4; ++h) {
        float v = (es[h] >= 0.f) ? es[h] : 0.2f * es[h];   // leaky_relu(0.2)
        es[h] = __expf(v);                                  // shift-free exp
    }
    uint4* rp = rec4 + ((size_t)mp * NEDGE + slot) * 2;
    rp[0] = make_uint4((unsigned)i0, (unsigned)i1, (unsigned)i2, 0u);
    *(float4*)&rp[1] = make_float4(es[0], es[1], es[2], es[3]);
}

// -------- weighted segment sum: linear records, depth-3 row pipeline --------
__global__ __launch_bounds__(256)
void seg_kernel(const int* __restrict__ rowptr4, const uint4* __restrict__ rec4,
                const unsigned short* __restrict__ tfb,
                unsigned short* __restrict__ gnb)
{
    int mp = blockIdx.y;
    int w = threadIdx.x >> 6, l = threadIdx.x & 63;
    int t = blockIdx.x * 4 + w;
    const int* rp = rowptr4 + mp * (NTGT + 1);
    const uint4* rec = rec4 + (size_t)mp * NEDGE * 2;
    const unsigned short* tfl = tfb + 2 * l;

    int beg = rp[t], end = rp[t + 1];
    int n = end - beg;
    float den[4] = {0, 0, 0, 0}, aa[4] = {0, 0, 0, 0}, ab[4] = {0, 0, 0, 0};
    const float inv3 = 1.f / 3.f;

    if (n > 0) {
        int last = n - 1;
        auto LDI = [&](int j, uint4& ia, float4& wv) {
            int jj = min(j, last);
            ia = rec[(size_t)(beg + jj) * 2];
            wv = *(const float4*)&rec[(size_t)(beg + jj) * 2 + 1];
        };
        uint4 I0, I1, I2, I3, I4;
        float4 W0v, W1v, W2v, W3v, W4v;
        LDI(0, I0, W0v); LDI(1, I1, W1v); LDI(2, I2, W2v); LDI(3, I3, W3v);
        unsigned int x0 = *(const unsigned int*)(tfl + (size_t)I0.x * 128);
        unsigned int x1 = *(const unsigned int*)(tfl + (size_t)I0.y * 128);
        unsigned int x2 = *(const unsigned int*)(tfl + (size_t)I0.z * 128);
        unsigned int y0 = *(const unsigned int*)(tfl + (size_t)I1.x * 128);
        unsigned int y1 = *(const unsigned int*)(tfl + (size_t)I1.y * 128);
        unsigned int y2 = *(const unsigned int*)(tfl + (size_t)I1.z * 128);
        unsigned int z0 = *(const unsigned int*)(tfl + (size_t)I2.x * 128);
        unsigned int z1 = *(const unsigned int*)(tfl + (size_t)I2.y * 128);
        unsigned int z2 = *(const unsigned int*)(tfl + (size_t)I2.z * 128);
        for (int i = 0; i < n; ++i) {
            unsigned int w0 = *(const unsigned int*)(tfl + (size_t)I3.x * 128);
            unsigned int w1 = *(const unsigned int*)(tfl + (size_t)I3.y * 128);
            unsigned int w2 = *(const unsigned int*)(tfl + (size_t)I3.z * 128);
            LDI(i + 4, I4, W4v);
            float fa = (bf2f((unsigned short)x0) + bf2f((unsigned short)x1) +
                        bf2f((unsigned short)x2)) * inv3;
            float fb = (bf2f((unsigned short)(x0 >> 16)) + bf2f((unsigned short)(x1 >> 16)) +
                        bf2f((unsigned short)(x2 >> 16))) * inv3;
            float es[4] = {W0v.x, W0v.y, W0v.z, W0v.w};
            #pragma unroll
            for (int h = 0; h < 4; ++h) {
                den[h] += es[h]; aa[h] += es[h] * fa; ab[h] += es[h] * fb;
            }
            x0 = y0; x1 = y1; x2 = y2;
            y0 = z0; y1 = z1; y2 = z2;
            z0 = w0; z1 = w1; z2 = w2;
            I3 = I4;
            W0v = W1v; W1v = W2v; W2v = W3v; W3v = W4v;
        }
    }

    unsigned short* gr = gnb + ((size_t)mp * NTGT + t) * 512;
    #pragma unroll
    for (int h = 0; h < 4; ++h) {
        float d = 1.f / (den[h] + 1e-9f);
        unsigned int lo = (unsigned int)(unsigned short)b16(aa[h] * d);
        unsigned int hi = (unsigned int)(unsigned short)b16(ab[h] * d);
        *(unsigned int*)(gr + h * 128 + 2 * l) = lo | (hi << 16);
    }
}

// ---------------- betas = softmax over pairs (both node types) --------------
__global__ void beta_kernel(const float* __restrict__ s, float* __restrict__ beta)
{
    int nt = threadIdx.x;
    if (nt < 2 && blockIdx.x == 0) {
        float b0 = s[nt * 2] * (1.f / 8192.f), b1 = s[nt * 2 + 1] * (1.f / 8192.f);
        float mm = fmaxf(b0, b1);
        float e0 = __expf(b0 - mm), e1 = __expf(b1 - mm);
        float d = e0 + e1;
        beta[nt * 2] = e0 / d;
        beta[nt * 2 + 1] = e1 / d;
    }
}

extern "C" void kernel_launch(void* const* d_in, const int* in_sizes, int n_in,
                              void* d_out, int out_size, void* d_ws, size_t ws_size,
                              hipStream_t stream)
{
    const float* feat0 = (const float*)d_in[0];
    const float* feat1 = (const float*)d_in[1];
    const int* nidx0 = (const int*)d_in[2];
    const int* nidx1 = (const int*)d_in[3];
    const int* eidx[4] = {(const int*)d_in[4], (const int*)d_in[6],
                          (const int*)d_in[8], (const int*)d_in[10]};
    const int* etgt[4] = {(const int*)d_in[5], (const int*)d_in[7],
                          (const int*)d_in[9], (const int*)d_in[11]};
    const float* W0 = (const float*)d_in[12]; const float* b0 = (const float*)d_in[13];
    const float* W1 = (const float*)d_in[14]; const float* b1 = (const float*)d_in[15];
    const float* Wr[4] = {(const float*)d_in[16], (const float*)d_in[18],
                          (const float*)d_in[25], (const float*)d_in[27]};
    const float* av[4] = {(const float*)d_in[17], (const float*)d_in[19],
                          (const float*)d_in[26], (const float*)d_in[28]};
    const float* Ws[2] = {(const float*)d_in[20], (const float*)d_in[29]};
    const float* bs[2] = {(const float*)d_in[21], (const float*)d_in[30]};
    const float* vsem[2] = {(const float*)d_in[22], (const float*)d_in[31]};
    const float* Wo[2] = {(const float*)d_in[23], (const float*)d_in[32]};
    const float* bo[2] = {(const float*)d_in[24], (const float*)d_in[33]};
    float* out = (float*)d_out;

    char* p = (char*)d_ws;
    auto carve = [&](size_t bytes) { char* r = p; p += (bytes + 255) & ~(size_t)255; return r; };
    unsigned short* tfb = (unsigned short*)carve((size_t)NNODES * 128 * 2);
    unsigned short* gnb = (unsigned short*)carve((size_t)4 * NTGT * 512 * 2);
    unsigned short* obb = (unsigned short*)carve((size_t)4 * NTGT * 512 * 2);
    float* snode        = (float*)carve((size_t)NNODES * 16 * 4);
    uint4* rec4         = (uint4*)carve((size_t)4 * NEDGE * 32);   // 12.8 MB
    int* rank4          = (int*)carve((size_t)4 * NEDGE * 4);      // 1.6 MB
    unsigned short* w0b = (unsigned short*)carve(65536 * 2);
    unsigned short* w1b = (unsigned short*)carve(65536 * 2);
    unsigned short* wrb = (unsigned short*)carve(4 * 65536 * 2);
    unsigned short* wsb = (unsigned short*)carve(2 * 65536 * 2);
    unsigned short* wob = (unsigned short*)carve(2 * 32768 * 2);
    unsigned short* wattp = (unsigned short*)carve(2048 * 2);
    float* ssem         = (float*)carve(4 * 4);
    float* betab        = (float*)carve(4 * 4);
    int* cnt4           = (int*)carve((size_t)4 * NTGT * 4);
    int* rowptr4        = (int*)carve((size_t)4 * (NTGT + 1) * 4);

    hipMemsetAsync(ssem, 0, 16, stream);
    hipMemsetAsync(cnt4, 0, (size_t)4 * NTGT * 4, stream);

    dim3 blk(256, 1, 1);

    PackArgs pa;
    pa.src[0] = W0; pa.dst[0] = w0b; pa.n16[0] = 8; pa.k32[0] = 16; pa.ld[0] = 512;
    pa.src[1] = W1; pa.dst[1] = w1b; pa.n16[1] = 8; pa.k32[1] = 16; pa.ld[1] = 512;
    for (int mp = 0; mp < 4; ++mp)
        for (int h = 0; h < 4; ++h) {
            int c = 2 + mp * 4 + h;
            pa.src[c] = Wr[mp] + (size_t)h * 128 * 128;
            pa.dst[c] = wrb + (size_t)(mp * 4 + h) * 16384;
            pa.n16[c] = 8; pa.k32[c] = 4; pa.ld[c] = 128;
        }
    pa.src[18] = Ws[0]; pa.dst[18] = wsb;         pa.n16[18] = 8; pa.k32[18] = 16; pa.ld[18] = 512;
    pa.src[19] = Ws[1]; pa.dst[19] = wsb + 65536; pa.n16[19] = 8; pa.k32[19] = 16; pa.ld[19] = 512;
    pa.src[20] = Wo[0]; pa.dst[20] = wob;         pa.n16[20] = 4; pa.k32[20] = 16; pa.ld[20] = 512;
    pa.src[21] = Wo[1]; pa.dst[21] = wob + 32768; pa.n16[21] = 4; pa.k32[21] = 16; pa.ld[21] = 512;
    pack_kernel<<<dim3(32, 22), blk, 0, stream>>>(pa);

    WattArgs wa;
    for (int mp = 0; mp < 4; ++mp) { wa.Wr[mp] = Wr[mp]; wa.a[mp] = av[mp]; }
    watt_kernel<<<dim3(8), blk, 0, stream>>>(wa, wattp);

    // typed node transform -> tfb (bf16), reg-staged bf16 LDS tiles
    {
        GArgs g = {};
        g.A[0] = feat0; g.A[1] = feat1;
        g.B[0] = w0b;   g.B[1] = w1b;
        g.bias[0] = b0; g.bias[1] = b1;
        g.C[0] = tfb;   g.C[1] = tfb;
        g.rowmap[0] = nidx0; g.rowmap[1] = nidx1;
        tgemm<<<dim3(1563, 1, 2), blk, 0, stream>>>(g, 50000);
    }

    // snode[node][16] = tfb @ watt^T (fp32 out)
    {
        GArgs g = {};
        g.A[0] = tfb;
        g.B[0] = wattp;
        g.C[0] = snode;
        mgemm<0, 1, 2, true, false, 1><<<dim3(782, 1, 1), blk, 0, stream>>>(
            g, 128, 16, 0, 0, 0, 0, NNODES, 128);
    }

    EArgs ea;
    for (int mp = 0; mp < 4; ++mp) { ea.eidx[mp] = eidx[mp]; ea.etgt[mp] = etgt[mp]; }

    hist_kernel<<<dim3(391, 4), blk, 0, stream>>>(ea, cnt4, rank4, NEDGE);
    scan_kernel<<<dim3(4), blk, 0, stream>>>(cnt4, rowptr4);
    scatter_esc<<<dim3(391, 4), blk, 0, stream>>>(ea, rowptr4, rank4, rec4,
                                                  snode, NEDGE);
    seg_kernel<<<dim3(NTGT / 4, 4), blk, 0, stream>>>(rowptr4, rec4, tfb, gnb);

    float* hout = out + (size_t)NTGT * 128;   // h regions: [2][NTGT][512]

    // EPI1: obb[mp] = elu(gn[mp]_h @ Wr[mp]_h^T) bf16, grid.y = head, grid.z = mp
    {
        GArgs g = {};
        for (int mp = 0; mp < 4; ++mp) {
            g.A[mp] = gnb + (size_t)mp * NTGT * 512;
            g.B[mp] = wrb + (size_t)mp * 65536;
            g.C[mp] = obb + (size_t)mp * NTGT * 512;
        }
        mgemm<1, 8, 2, true, true, 8><<<dim3(64, 4, 4), blk, 0, stream>>>(
            g, 512, 512, 128, 16384, 128, 0, NTGT, 128);
    }

    // EPI2: ssem[mp] += sum tanh(obb[mp] @ Ws^T + bs) . vs  (grid.y = N-half)
    {
        GArgs g = {};
        for (int mp = 0; mp < 4; ++mp) {
            int nt = mp >> 1;
            g.A[mp] = obb + (size_t)mp * NTGT * 512;
            g.B[mp] = wsb + (size_t)nt * 65536;
            g.bias[mp] = bs[nt];
            g.vs[mp] = vsem[nt];
            g.sem[mp] = ssem + mp;
        }
        mgemm<2, 4, 1, true, false, 8><<<dim3(128, 2, 4), blk, 0, stream>>>(
            g, 512, 0, 0, 2048, 0, 64, NTGT, 512);
    }

    beta_kernel<<<dim3(1), dim3(64), 0, stream>>>(ssem, betab);

    // fused combine + logits: h (fp32) + logits, one pass over obb
    flogits<<<dim3(128, 1, 2), blk, 0, stream>>>(obb, wob, betab,
                                                 bo[0], bo[1], out, hout);
}

// Round 17
// 257.373 us; speedup vs baseline: 1.0362x; 1.0362x over previous
//
#include <hip/hip_runtime.h>
#include <hip/hip_bf16.h>
#include <math.h>

// MAGNN-style hetero-GAT forward, R17.
// - tgemm: 512-thread / 64-row blocks (8 waves, 64KB LDS). Halves per-row
//   B-frag L2 traffic (B re-read amortized over 64 rows) and raises waves/CU
//   12->16. Tests the L2-B-contention theory for the stubborn ~91us.
// - EPI2 reverted to NF=8 single-N (the N-split doubled A reads).

#define HIDDEN 128
#define HEADS 4
#define NTGT 8192
#define NEDGE 100000
#define NNODES 100000

typedef __attribute__((ext_vector_type(8))) short bf16x8;
typedef __attribute__((ext_vector_type(4))) float f32x4;

__device__ inline short b16(float f)
{
    union { __hip_bfloat16 h; short s; } u;
    u.h = __float2bfloat16(f);
    return u.s;
}

__device__ inline float bf2f(unsigned short u)
{
    union { unsigned int i; float f; } v;
    v.i = (unsigned int)u << 16;
    return v.f;
}

struct GArgs {   // per-blockIdx.z pointers
    const void* A[4];
    const unsigned short* B[4];   // packed frag-major
    const float* bias[4];
    void* C[4];
    const int* rowmap[4];
    const float* vs[4];
    float* sem[4];
};

// ------------- transform GEMM: 8-wave 64-row blocks, bf16 LDS --------------
// LDS bf16[64][512] = 64KB. Wave w stages rows w*8..w*8+7 (contiguous 1KB
// float4 loads, per-row XOR granule swizzle on ds_write). Compute: wave w ->
// rowfrag (w&3), colfrags (w>>2)*4..+4.
__global__ __launch_bounds__(512, 1)
void tgemm(GArgs g, int M)
{
    __shared__ unsigned short lds[64 * 512];   // 64KB bf16
    const int z = blockIdx.z;
    const float* Af = (const float*)g.A[z];
    const unsigned short* Bp = g.B[z];
    const float* bias = g.bias[z];
    const int* rowmap = g.rowmap[z];
    unsigned short* Ch = (unsigned short*)g.C[z];

    const int tid = threadIdx.x;
    const int w = tid >> 6, l = tid & 63;
    const int lr = l & 15, s4 = l >> 4;
    const int m0 = blockIdx.x * 64;

    {
        float4 v[16];
        #pragma unroll
        for (int q = 0; q < 8; ++q) {
            int rg = min(m0 + w * 8 + q, M - 1);
            const float* rowp = Af + (size_t)rg * 512;
            v[2 * q]     = *(const float4*)(rowp + l * 4);
            v[2 * q + 1] = *(const float4*)(rowp + 256 + l * 4);
        }
        #pragma unroll
        for (int q = 0; q < 8; ++q) {
            int rl = w * 8 + q;
            int rx = rl & 7;                    // == q
            #pragma unroll
            for (int hh = 0; hh < 2; ++hh) {
                float4 vv = v[2 * q + hh];
                uint2 pk;
                pk.x = (unsigned int)(unsigned short)b16(vv.x) |
                       ((unsigned int)(unsigned short)b16(vv.y) << 16);
                pk.y = (unsigned int)(unsigned short)b16(vv.z) |
                       ((unsigned int)(unsigned short)b16(vv.w) << 16);
                int G = hh * 32 + (l >> 1);
                int slot = (G & ~7) | ((G & 7) ^ rx);
                *(uint2*)((char*)lds + (size_t)rl * 1024 + slot * 16 + (l & 1) * 8) = pk;
            }
        }
    }

    const int i = w & 3;           // rowfrag 0..3
    const int jb = (w >> 2) * 4;   // colfrag base 0 or 4

    f32x4 acc[4];
    #pragma unroll
    for (int jj = 0; jj < 4; ++jj) acc[jj] = (f32x4){0.f, 0.f, 0.f, 0.f};

    bf16x8 bbA[4], bbB[4];
    auto LDB = [&](int c, bf16x8 (&bb)[4]) {
        #pragma unroll
        for (int jj = 0; jj < 4; ++jj)
            bb[jj] = *(const bf16x8*)(Bp + ((size_t)(c * 8 + jb + jj) * 64 + l) * 8);
    };

    LDB(0, bbA);
    __syncthreads();

    const int r = i * 16 + lr;     // row within 64-row tile
    const int rx = r & 7;

    #pragma unroll
    for (int c = 0; c < 16; ++c) {
        int G = 4 * c + s4;
        int slot = (G & ~7) | ((G & 7) ^ rx);
        bf16x8 a = *(const bf16x8*)((const char*)lds + (size_t)r * 1024 + slot * 16);
        if (c & 1) {
            if (c + 1 < 16) LDB(c + 1, bbA);
            #pragma unroll
            for (int jj = 0; jj < 4; ++jj)
                acc[jj] = __builtin_amdgcn_mfma_f32_16x16x32_bf16(a, bbB[jj], acc[jj], 0, 0, 0);
        } else {
            if (c + 1 < 16) LDB(c + 1, bbB);
            #pragma unroll
            for (int jj = 0; jj < 4; ++jj)
                acc[jj] = __builtin_amdgcn_mfma_f32_16x16x32_bf16(a, bbA[jj], acc[jj], 0, 0, 0);
        }
    }

    #pragma unroll
    for (int rr = 0; rr < 4; ++rr) {
        int gm = m0 + i * 16 + s4 * 4 + rr;
        if (gm >= M) continue;
        size_t crow = (size_t)rowmap[gm];
        #pragma unroll
        for (int jj = 0; jj < 4; ++jj) {
            int n = (jb + jj) * 16 + lr;
            Ch[crow * 128 + n] = (unsigned short)b16(acc[jj][rr] + bias[n]);
        }
    }
}

// ---------------- unified MFMA GEMM (2-stage): C = A(->bf16) * Bpacked ------
template<int EPI, int NF, int MI, bool AB16, bool C16, int NFS>
__global__ __launch_bounds__(256)
void mgemm(GArgs g, int lda, int ldc,
           int aOffY, int bOffY, int cOffY, int nOffY, int M, int K)
{
    __shared__ float red[4];
    const int z = blockIdx.z;
    const unsigned short* Bp = g.B[z] + (size_t)blockIdx.y * bOffY;
    const float* bias = g.bias[z];
    const int* rowmap = g.rowmap[z];
    const int nbase = blockIdx.y * nOffY;
    float* Cf = nullptr;
    unsigned short* Ch = nullptr;
    if (g.C[z]) {
        if (C16) Ch = (unsigned short*)g.C[z] + (size_t)blockIdx.y * cOffY;
        else     Cf = (float*)g.C[z] + (size_t)blockIdx.y * cOffY;
    }
    const float* Af = nullptr;
    const unsigned short* Ah = nullptr;
    if (AB16) Ah = (const unsigned short*)g.A[z] + (size_t)blockIdx.y * aOffY;
    else      Af = (const float*)g.A[z] + (size_t)blockIdx.y * aOffY;

    const int tid = threadIdx.x;
    const int w = tid >> 6, l = tid & 63;
    const int lr = l & 15, lk = (l >> 4) * 8;
    const int m0 = blockIdx.x * (MI * 64) + w * (MI * 16);

    f32x4 acc[MI][NF];
    #pragma unroll
    for (int i = 0; i < MI; ++i)
        #pragma unroll
        for (int j = 0; j < NF; ++j)
            acc[i][j] = (f32x4){0.f, 0.f, 0.f, 0.f};

    float4 af0[MI][2], af1[MI][2];
    bf16x8 ah0[MI], ah1[MI];
    bf16x8 bb0[NF], bb1[NF];

    auto LD = [&](int k0, float4 (&af)[MI][2], bf16x8 (&ah)[MI], bf16x8 (&bb)[NF]) {
        #pragma unroll
        for (int i = 0; i < MI; ++i) {
            int row = min(m0 + i * 16 + lr, M - 1);
            if (AB16) {
                ah[i] = *(const bf16x8*)(Ah + (size_t)row * lda + k0 + lk);
            } else {
                const float* p = Af + (size_t)row * lda + k0 + lk;
                af[i][0] = *(const float4*)p;
                af[i][1] = *(const float4*)(p + 4);
            }
        }
        #pragma unroll
        for (int j = 0; j < NF; ++j)
            bb[j] = *(const bf16x8*)(Bp + ((size_t)((k0 >> 5) * NFS + j) * 64 + l) * 8);
    };

    auto CMP = [&](float4 (&af)[MI][2], bf16x8 (&ah)[MI], bf16x8 (&bb)[NF]) {
        bf16x8 a[MI];
        #pragma unroll
        for (int i = 0; i < MI; ++i) {
            if (AB16) {
                a[i] = ah[i];
            } else {
                bf16x8 r;
                r[0] = b16(af[i][0].x); r[1] = b16(af[i][0].y);
                r[2] = b16(af[i][0].z); r[3] = b16(af[i][0].w);
                r[4] = b16(af[i][1].x); r[5] = b16(af[i][1].y);
                r[6] = b16(af[i][1].z); r[7] = b16(af[i][1].w);
                a[i] = r;
            }
        }
        #pragma unroll
        for (int j = 0; j < NF; ++j)
            #pragma unroll
            for (int i = 0; i < MI; ++i)
                acc[i][j] = __builtin_amdgcn_mfma_f32_16x16x32_bf16(a[i], bb[j], acc[i][j], 0, 0, 0);
    };

    LD(0, af0, ah0, bb0);
    for (int k0 = 0; k0 < K; k0 += 64) {
        LD(k0 + 32, af1, ah1, bb1);
        CMP(af0, ah0, bb0);
        if (k0 + 64 < K) LD(k0 + 64, af0, ah0, bb0);
        CMP(af1, ah1, bb1);
    }

    if (EPI == 2) {
        const float* vs = g.vs[z];
        float local = 0.f;
        #pragma unroll
        for (int i = 0; i < MI; ++i) {
            int rbase = m0 + i * 16 + (l >> 4) * 4;
            #pragma unroll
            for (int r = 0; r < 4; ++r) {
                if (rbase + r >= M) continue;
                #pragma unroll
                for (int j = 0; j < NF; ++j) {
                    int n = nbase + j * 16 + lr;
                    local += tanhf(acc[i][j][r] + bias[n]) * vs[n];
                }
            }
        }
        #pragma unroll
        for (int o = 32; o; o >>= 1) local += __shfl_xor(local, o, 64);
        if (l == 0) red[w] = local;
        __syncthreads();
        if (tid == 0) atomicAdd(g.sem[z], red[0] + red[1] + red[2] + red[3]);
        return;
    }

    #pragma unroll
    for (int i = 0; i < MI; ++i) {
        int rbase = m0 + i * 16 + (l >> 4) * 4;
        #pragma unroll
        for (int r = 0; r < 4; ++r) {
            int gm = rbase + r;
            if (gm >= M) continue;
            size_t crow = rowmap ? (size_t)rowmap[gm] : (size_t)gm;
            #pragma unroll
            for (int j = 0; j < NF; ++j) {
                int n = nbase + j * 16 + lr;
                float v = acc[i][j][r];
                if (EPI == 0 && bias) v += bias[n];
                if (EPI == 1) v = v > 0.f ? v : expm1f(v);
                if (C16) Ch[crow * (size_t)ldc + n] = (unsigned short)b16(v);
                else     Cf[crow * (size_t)ldc + n] = v;
            }
        }
    }
}

// -------- fused combine+logits: h = b0*ob0+b1*ob1 (fp32 out, inline),
// logits = h @ Wo^T + bo. grid (128, 1, 2=nt); block = 64 rows, wave = 16.
__global__ __launch_bounds__(256)
void flogits(const unsigned short* __restrict__ obb,
             const unsigned short* __restrict__ wob,
             const float* __restrict__ betab,
             const float* __restrict__ bo0, const float* __restrict__ bo1,
             float* __restrict__ outbase, float* __restrict__ hout)
{
    const int nt = blockIdx.z;
    const unsigned short* o0 = obb + (size_t)(2 * nt) * NTGT * 512;
    const unsigned short* o1 = obb + (size_t)(2 * nt + 1) * NTGT * 512;
    const unsigned short* Bp = wob + (size_t)nt * 32768;
    const float* bo = nt ? bo1 : bo0;
    const float b0 = betab[nt * 2], b1 = betab[nt * 2 + 1];

    const int tid = threadIdx.x;
    const int w = tid >> 6, l = tid & 63;
    const int lr = l & 15, s4 = l >> 4, lk = s4 * 8;
    const int row = blockIdx.x * 64 + w * 16 + lr;
    float* hrow = hout + ((size_t)nt * NTGT + row) * 512;

    f32x4 acc[4];
    #pragma unroll
    for (int j = 0; j < 4; ++j) acc[j] = (f32x4){0.f, 0.f, 0.f, 0.f};

    for (int k0 = 0; k0 < 512; k0 += 32) {
        bf16x8 a0 = *(const bf16x8*)(o0 + (size_t)row * 512 + k0 + lk);
        bf16x8 a1 = *(const bf16x8*)(o1 + (size_t)row * 512 + k0 + lk);
        float hv[8];
        bf16x8 af;
        #pragma unroll
        for (int j = 0; j < 8; ++j) {
            hv[j] = b0 * bf2f((unsigned short)a0[j]) + b1 * bf2f((unsigned short)a1[j]);
            af[j] = b16(hv[j]);
        }
        *(float4*)(hrow + k0 + lk)     = make_float4(hv[0], hv[1], hv[2], hv[3]);
        *(float4*)(hrow + k0 + lk + 4) = make_float4(hv[4], hv[5], hv[6], hv[7]);
        #pragma unroll
        for (int j = 0; j < 4; ++j) {
            bf16x8 bb = *(const bf16x8*)(Bp + ((size_t)((k0 >> 5) * 4 + j) * 64 + l) * 8);
            acc[j] = __builtin_amdgcn_mfma_f32_16x16x32_bf16(af, bb, acc[j], 0, 0, 0);
        }
    }

    float* lout = outbase + (size_t)nt * NTGT * 64;
    #pragma unroll
    for (int r = 0; r < 4; ++r) {
        int gm = blockIdx.x * 64 + w * 16 + s4 * 4 + r;
        #pragma unroll
        for (int j = 0; j < 4; ++j) {
            int n = j * 16 + lr;
            lout[(size_t)gm * 64 + n] = acc[j][r] + bo[n];
        }
    }
}

// ------- pack fp32 weight matrices -> bf16 MFMA frag-major layout -----------
struct PackArgs {
    const float* src[22];
    unsigned short* dst[22];
    int n16[22], k32[22], ld[22];
};

__global__ __launch_bounds__(256)
void pack_kernel(PackArgs pa)
{
    int c = blockIdx.y;
    int idx = blockIdx.x * 256 + threadIdx.x;
    int tot = pa.n16[c] * pa.k32[c] * 64;
    if (idx >= tot) return;
    int l = idx & 63;
    int rest = idx >> 6;
    int j = rest % pa.n16[c];
    int k0 = rest / pa.n16[c];
    int row = j * 16 + (l & 15);
    int col = k0 * 32 + (l >> 4) * 8;
    const float* s = pa.src[c] + (size_t)row * pa.ld[c] + col;
    float4 u = *(const float4*)s;
    float4 v = *(const float4*)(s + 4);
    bf16x8 r;
    r[0] = b16(u.x); r[1] = b16(u.y); r[2] = b16(u.z); r[3] = b16(u.w);
    r[4] = b16(v.x); r[5] = b16(v.y); r[6] = b16(v.z); r[7] = b16(v.w);
    *(bf16x8*)(pa.dst[c] + (size_t)idx * 8) = r;
}

// --- watt (fused pack): wattp[idx] = b16( sum_d a[mp][h,d]*Wr[mp][h*128+d,k] )
struct WattArgs { const float* Wr[4]; const float* a[4]; };

__global__ __launch_bounds__(256)
void watt_kernel(WattArgs wa, unsigned short* __restrict__ wattp)
{
    int idx = blockIdx.x * 256 + threadIdx.x;   // 0..2047
    int f = idx >> 9;
    int r = idx & 511;
    int l = r >> 3;
    int e = r & 7;
    int row = l & 15;
    int k = f * 32 + ((l >> 4) << 3) + e;
    int mp = row >> 2, h = row & 3;
    const float* Wr = wa.Wr[mp];
    const float* a = wa.a[mp];
    float s = 0.f;
    #pragma unroll 4
    for (int d = 0; d < HIDDEN; ++d)
        s += a[h * HIDDEN + d] * Wr[(size_t)(h * HIDDEN + d) * HIDDEN + k];
    wattp[idx] = (unsigned short)b16(s);
}

// ---------------- CSR build: hist (with rank) / scan / scatter_esc ----------
struct EArgs { const int* eidx[4]; const int* etgt[4]; };

__global__ __launch_bounds__(256)
void hist_kernel(EArgs ea, int* __restrict__ cnt4, int* __restrict__ rank4, int E)
{
    int e = blockIdx.x * 256 + threadIdx.x;
    int mp = blockIdx.y;
    if (e < E)
        rank4[(size_t)mp * NEDGE + e] = atomicAdd(&cnt4[mp * NTGT + ea.etgt[mp][e]], 1);
}

__global__ __launch_bounds__(256)
void scan_kernel(int* __restrict__ cnt4, int* __restrict__ rowptr4)
{
    int mp = blockIdx.x;
    int* cnt = cnt4 + mp * NTGT;
    int* rowptr = rowptr4 + mp * (NTGT + 1);
    __shared__ int part[256];
    int t = threadIdx.x;
    int vals[32];
    int s = 0;
    int base = t * 32;
    #pragma unroll
    for (int i = 0; i < 32; ++i) { vals[i] = cnt[base + i]; s += vals[i]; }
    part[t] = s;
    __syncthreads();
    for (int o = 1; o < 256; o <<= 1) {
        int v = (t >= o) ? part[t - o] : 0;
        __syncthreads();
        part[t] += v;
        __syncthreads();
    }
    int off = (t == 0) ? 0 : part[t - 1];
    #pragma unroll
    for (int i = 0; i < 32; ++i) { rowptr[base + i] = off; off += vals[i]; }
    if (t == 255) rowptr[NTGT] = off;
}

// scatter (ATOMIC-FREE via rank) + edge exp-weight -> CSR-ordered 32B records
__global__ __launch_bounds__(256)
void scatter_esc(EArgs ea, const int* __restrict__ rowptr4,
                 const int* __restrict__ rank4, uint4* __restrict__ rec4,
                 const float* __restrict__ snode, int E)
{
    int e = blockIdx.x * 256 + threadIdx.x;
    int mp = blockIdx.y;
    if (e >= E) return;
    int t = ea.etgt[mp][e];
    int slot = rowptr4[mp * (NTGT + 1) + t] + rank4[(size_t)mp * NEDGE + e];

    const int* eidx = ea.eidx[mp];
    int i0 = eidx[e * 3 + 0], i1 = eidx[e * 3 + 1], i2 = eidx[e * 3 + 2];
    float4 s0 = *(const float4*)(snode + (size_t)i0 * 16 + mp * 4);
    float4 s1 = *(const float4*)(snode + (size_t)i1 * 16 + mp * 4);
    float4 s2 = *(const float4*)(snode + (size_t)i2 * 16 + mp * 4);
    const float inv3 = 1.f / 3.f;
    float es[4];
    es[0] = (s0.x + s1.x + s2.x) * inv3;
    es[1] = (s0.y + s1.y + s2.y) * inv3;
    es[2] = (s0.z + s1.z + s2.z) * inv3;
    es[3] = (s0.w + s1.w + s2.w) * inv3;
    #pragma unroll
    for (int h = 0; h < 4; ++h) {
        float v = (es[h] >= 0.f) ? es[h] : 0.2f * es[h];   // leaky_relu(0.2)
        es[h] = __expf(v);                                  // shift-free exp
    }
    uint4* rp = rec4 + ((size_t)mp * NEDGE + slot) * 2;
    rp[0] = make_uint4((unsigned)i0, (unsigned)i1, (unsigned)i2, 0u);
    *(float4*)&rp[1] = make_float4(es[0], es[1], es[2], es[3]);
}

// -------- weighted segment sum: linear records, depth-3 row pipeline --------
__global__ __launch_bounds__(256)
void seg_kernel(const int* __restrict__ rowptr4, const uint4* __restrict__ rec4,
                const unsigned short* __restrict__ tfb,
                unsigned short* __restrict__ gnb)
{
    int mp = blockIdx.y;
    int w = threadIdx.x >> 6, l = threadIdx.x & 63;
    int t = blockIdx.x * 4 + w;
    const int* rp = rowptr4 + mp * (NTGT + 1);
    const uint4* rec = rec4 + (size_t)mp * NEDGE * 2;
    const unsigned short* tfl = tfb + 2 * l;

    int beg = rp[t], end = rp[t + 1];
    int n = end - beg;
    float den[4] = {0, 0, 0, 0}, aa[4] = {0, 0, 0, 0}, ab[4] = {0, 0, 0, 0};
    const float inv3 = 1.f / 3.f;

    if (n > 0) {
        int last = n - 1;
        auto LDI = [&](int j, uint4& ia, float4& wv) {
            int jj = min(j, last);
            ia = rec[(size_t)(beg + jj) * 2];
            wv = *(const float4*)&rec[(size_t)(beg + jj) * 2 + 1];
        };
        uint4 I0, I1, I2, I3, I4;
        float4 W0v, W1v, W2v, W3v, W4v;
        LDI(0, I0, W0v); LDI(1, I1, W1v); LDI(2, I2, W2v); LDI(3, I3, W3v);
        unsigned int x0 = *(const unsigned int*)(tfl + (size_t)I0.x * 128);
        unsigned int x1 = *(const unsigned int*)(tfl + (size_t)I0.y * 128);
        unsigned int x2 = *(const unsigned int*)(tfl + (size_t)I0.z * 128);
        unsigned int y0 = *(const unsigned int*)(tfl + (size_t)I1.x * 128);
        unsigned int y1 = *(const unsigned int*)(tfl + (size_t)I1.y * 128);
        unsigned int y2 = *(const unsigned int*)(tfl + (size_t)I1.z * 128);
        unsigned int z0 = *(const unsigned int*)(tfl + (size_t)I2.x * 128);
        unsigned int z1 = *(const unsigned int*)(tfl + (size_t)I2.y * 128);
        unsigned int z2 = *(const unsigned int*)(tfl + (size_t)I2.z * 128);
        for (int i = 0; i < n; ++i) {
            unsigned int w0 = *(const unsigned int*)(tfl + (size_t)I3.x * 128);
            unsigned int w1 = *(const unsigned int*)(tfl + (size_t)I3.y * 128);
            unsigned int w2 = *(const unsigned int*)(tfl + (size_t)I3.z * 128);
            LDI(i + 4, I4, W4v);
            float fa = (bf2f((unsigned short)x0) + bf2f((unsigned short)x1) +
                        bf2f((unsigned short)x2)) * inv3;
            float fb = (bf2f((unsigned short)(x0 >> 16)) + bf2f((unsigned short)(x1 >> 16)) +
                        bf2f((unsigned short)(x2 >> 16))) * inv3;
            float es[4] = {W0v.x, W0v.y, W0v.z, W0v.w};
            #pragma unroll
            for (int h = 0; h < 4; ++h) {
                den[h] += es[h]; aa[h] += es[h] * fa; ab[h] += es[h] * fb;
            }
            x0 = y0; x1 = y1; x2 = y2;
            y0 = z0; y1 = z1; y2 = z2;
            z0 = w0; z1 = w1; z2 = w2;
            I3 = I4;
            W0v = W1v; W1v = W2v; W2v = W3v; W3v = W4v;
        }
    }

    unsigned short* gr = gnb + ((size_t)mp * NTGT + t) * 512;
    #pragma unroll
    for (int h = 0; h < 4; ++h) {
        float d = 1.f / (den[h] + 1e-9f);
        unsigned int lo = (unsigned int)(unsigned short)b16(aa[h] * d);
        unsigned int hi = (unsigned int)(unsigned short)b16(ab[h] * d);
        *(unsigned int*)(gr + h * 128 + 2 * l) = lo | (hi << 16);
    }
}

// ---------------- betas = softmax over pairs (both node types) --------------
__global__ void beta_kernel(const float* __restrict__ s, float* __restrict__ beta)
{
    int nt = threadIdx.x;
    if (nt < 2 && blockIdx.x == 0) {
        float b0 = s[nt * 2] * (1.f / 8192.f), b1 = s[nt * 2 + 1] * (1.f / 8192.f);
        float mm = fmaxf(b0, b1);
        float e0 = __expf(b0 - mm), e1 = __expf(b1 - mm);
        float d = e0 + e1;
        beta[nt * 2] = e0 / d;
        beta[nt * 2 + 1] = e1 / d;
    }
}

extern "C" void kernel_launch(void* const* d_in, const int* in_sizes, int n_in,
                              void* d_out, int out_size, void* d_ws, size_t ws_size,
                              hipStream_t stream)
{
    const float* feat0 = (const float*)d_in[0];
    const float* feat1 = (const float*)d_in[1];
    const int* nidx0 = (const int*)d_in[2];
    const int* nidx1 = (const int*)d_in[3];
    const int* eidx[4] = {(const int*)d_in[4], (const int*)d_in[6],
                          (const int*)d_in[8], (const int*)d_in[10]};
    const int* etgt[4] = {(const int*)d_in[5], (const int*)d_in[7],
                          (const int*)d_in[9], (const int*)d_in[11]};
    const float* W0 = (const float*)d_in[12]; const float* b0 = (const float*)d_in[13];
    const float* W1 = (const float*)d_in[14]; const float* b1 = (const float*)d_in[15];
    const float* Wr[4] = {(const float*)d_in[16], (const float*)d_in[18],
                          (const float*)d_in[25], (const float*)d_in[27]};
    const float* av[4] = {(const float*)d_in[17], (const float*)d_in[19],
                          (const float*)d_in[26], (const float*)d_in[28]};
    const float* Ws[2] = {(const float*)d_in[20], (const float*)d_in[29]};
    const float* bs[2] = {(const float*)d_in[21], (const float*)d_in[30]};
    const float* vsem[2] = {(const float*)d_in[22], (const float*)d_in[31]};
    const float* Wo[2] = {(const float*)d_in[23], (const float*)d_in[32]};
    const float* bo[2] = {(const float*)d_in[24], (const float*)d_in[33]};
    float* out = (float*)d_out;

    char* p = (char*)d_ws;
    auto carve = [&](size_t bytes) { char* r = p; p += (bytes + 255) & ~(size_t)255; return r; };
    unsigned short* tfb = (unsigned short*)carve((size_t)NNODES * 128 * 2);
    unsigned short* gnb = (unsigned short*)carve((size_t)4 * NTGT * 512 * 2);
    unsigned short* obb = (unsigned short*)carve((size_t)4 * NTGT * 512 * 2);
    float* snode        = (float*)carve((size_t)NNODES * 16 * 4);
    uint4* rec4         = (uint4*)carve((size_t)4 * NEDGE * 32);   // 12.8 MB
    int* rank4          = (int*)carve((size_t)4 * NEDGE * 4);      // 1.6 MB
    unsigned short* w0b = (unsigned short*)carve(65536 * 2);
    unsigned short* w1b = (unsigned short*)carve(65536 * 2);
    unsigned short* wrb = (unsigned short*)carve(4 * 65536 * 2);
    unsigned short* wsb = (unsigned short*)carve(2 * 65536 * 2);
    unsigned short* wob = (unsigned short*)carve(2 * 32768 * 2);
    unsigned short* wattp = (unsigned short*)carve(2048 * 2);
    float* ssem         = (float*)carve(4 * 4);
    float* betab        = (float*)carve(4 * 4);
    int* cnt4           = (int*)carve((size_t)4 * NTGT * 4);
    int* rowptr4        = (int*)carve((size_t)4 * (NTGT + 1) * 4);

    hipMemsetAsync(ssem, 0, 16, stream);
    hipMemsetAsync(cnt4, 0, (size_t)4 * NTGT * 4, stream);

    dim3 blk(256, 1, 1);

    PackArgs pa;
    pa.src[0] = W0; pa.dst[0] = w0b; pa.n16[0] = 8; pa.k32[0] = 16; pa.ld[0] = 512;
    pa.src[1] = W1; pa.dst[1] = w1b; pa.n16[1] = 8; pa.k32[1] = 16; pa.ld[1] = 512;
    for (int mp = 0; mp < 4; ++mp)
        for (int h = 0; h < 4; ++h) {
            int c = 2 + mp * 4 + h;
            pa.src[c] = Wr[mp] + (size_t)h * 128 * 128;
            pa.dst[c] = wrb + (size_t)(mp * 4 + h) * 16384;
            pa.n16[c] = 8; pa.k32[c] = 4; pa.ld[c] = 128;
        }
    pa.src[18] = Ws[0]; pa.dst[18] = wsb;         pa.n16[18] = 8; pa.k32[18] = 16; pa.ld[18] = 512;
    pa.src[19] = Ws[1]; pa.dst[19] = wsb + 65536; pa.n16[19] = 8; pa.k32[19] = 16; pa.ld[19] = 512;
    pa.src[20] = Wo[0]; pa.dst[20] = wob;         pa.n16[20] = 4; pa.k32[20] = 16; pa.ld[20] = 512;
    pa.src[21] = Wo[1]; pa.dst[21] = wob + 32768; pa.n16[21] = 4; pa.k32[21] = 16; pa.ld[21] = 512;
    pack_kernel<<<dim3(32, 22), blk, 0, stream>>>(pa);

    WattArgs wa;
    for (int mp = 0; mp < 4; ++mp) { wa.Wr[mp] = Wr[mp]; wa.a[mp] = av[mp]; }
    watt_kernel<<<dim3(8), blk, 0, stream>>>(wa, wattp);

    // typed node transform -> tfb (bf16), 8-wave 64-row blocks
    {
        GArgs g = {};
        g.A[0] = feat0; g.A[1] = feat1;
        g.B[0] = w0b;   g.B[1] = w1b;
        g.bias[0] = b0; g.bias[1] = b1;
        g.C[0] = tfb;   g.C[1] = tfb;
        g.rowmap[0] = nidx0; g.rowmap[1] = nidx1;
        tgemm<<<dim3(782, 1, 2), dim3(512), 0, stream>>>(g, 50000);
    }

    // snode[node][16] = tfb @ watt^T (fp32 out)
    {
        GArgs g = {};
        g.A[0] = tfb;
        g.B[0] = wattp;
        g.C[0] = snode;
        mgemm<0, 1, 2, true, false, 1><<<dim3(782, 1, 1), blk, 0, stream>>>(
            g, 128, 16, 0, 0, 0, 0, NNODES, 128);
    }

    EArgs ea;
    for (int mp = 0; mp < 4; ++mp) { ea.eidx[mp] = eidx[mp]; ea.etgt[mp] = etgt[mp]; }

    hist_kernel<<<dim3(391, 4), blk, 0, stream>>>(ea, cnt4, rank4, NEDGE);
    scan_kernel<<<dim3(4), blk, 0, stream>>>(cnt4, rowptr4);
    scatter_esc<<<dim3(391, 4), blk, 0, stream>>>(ea, rowptr4, rank4, rec4,
                                                  snode, NEDGE);
    seg_kernel<<<dim3(NTGT / 4, 4), blk, 0, stream>>>(rowptr4, rec4, tfb, gnb);

    float* hout = out + (size_t)NTGT * 128;   // h regions: [2][NTGT][512]

    // EPI1: obb[mp] = elu(gn[mp]_h @ Wr[mp]_h^T) bf16, grid.y = head, grid.z = mp
    {
        GArgs g = {};
        for (int mp = 0; mp < 4; ++mp) {
            g.A[mp] = gnb + (size_t)mp * NTGT * 512;
            g.B[mp] = wrb + (size_t)mp * 65536;
            g.C[mp] = obb + (size_t)mp * NTGT * 512;
        }
        mgemm<1, 8, 2, true, true, 8><<<dim3(64, 4, 4), blk, 0, stream>>>(
            g, 512, 512, 128, 16384, 128, 0, NTGT, 128);
    }

    // EPI2: ssem[mp] += sum tanh(obb[mp] @ Ws^T + bs) . vs  (single-N, NF=8)
    {
        GArgs g = {};
        for (int mp = 0; mp < 4; ++mp) {
            int nt = mp >> 1;
            g.A[mp] = obb + (size_t)mp * NTGT * 512;
            g.B[mp] = wsb + (size_t)nt * 65536;
            g.bias[mp] = bs[nt];
            g.vs[mp] = vsem[nt];
            g.sem[mp] = ssem + mp;
        }
        mgemm<2, 8, 1, true, false, 8><<<dim3(128, 1, 4), blk, 0, stream>>>(
            g, 512, 0, 0, 0, 0, 0, NTGT, 512);
    }

    beta_kernel<<<dim3(1), dim3(64), 0, stream>>>(ssem, betab);

    // fused combine + logits: h (fp32) + logits, one pass over obb
    flogits<<<dim3(128, 1, 2), blk, 0, stream>>>(obb, wob, betab,
                                                 bo[0], bo[1], out, hout);
}